// Round 7
// baseline (281.000 us; speedup 1.0000x reference)
//
#include <hip/hip_runtime.h>

#define DEV __device__ __forceinline__

typedef unsigned short u16;
typedef short bf16x8 __attribute__((ext_vector_type(8)));
typedef float f32x4 __attribute__((ext_vector_type(4)));

// ---- problem constants (match reference) ----
#define BB    32
#define NOBJ  16
#define NREL  64
#define CCH   1024
#define FHW   50
#define HW    2500      // 50*50
#define NROI  512       // BB*NOBJ
#define MROWS 25088     // NROI*49  (= 196*128)
#define D1    1024
#define D2    512

DEV u16 f2bf(float f) {
  unsigned u = __float_as_uint(f);
  unsigned r = (u + 0x7FFFu + ((u >> 16) & 1u)) >> 16;
  return (u16)r;
}
DEV float bf2f(u16 h) { return __uint_as_float((unsigned)h << 16); }
DEV unsigned pk(float lo, float hi) { return (unsigned)f2bf(lo) | ((unsigned)f2bf(hi) << 16); }

using gvoid = __attribute__((address_space(1))) const void;
using svoid = __attribute__((address_space(3))) void;
DEV void gl_lds16(const void* g, void* s) {
  __builtin_amdgcn_global_load_lds((gvoid*)g, (svoid*)s, 16, 0, 0);
}

// ---------------- shared 64x64 transpose tile (f32 -> bf16) ----------------
// in: (R, C) f32 ; writes out[(c0+c)*R + r0+r] bf16 for the 64x64 tile.
DEV void transpose_tile(const float* __restrict__ in, u16* __restrict__ out,
                        int R, int C, int c0, int r0, int t) {
  __shared__ float tile[64][65];
  {
    const int rr = t >> 4;
    const int cq = (t & 15) * 4;
#pragma unroll
    for (int it = 0; it < 4; ++it) {
      int rl = rr + it * 16;
      int r = r0 + rl;
      int c = c0 + cq;
      if (c + 3 < C) {
        float4 v = *reinterpret_cast<const float4*>(&in[(size_t)r * C + c]);
        tile[rl][cq + 0] = v.x; tile[rl][cq + 1] = v.y;
        tile[rl][cq + 2] = v.z; tile[rl][cq + 3] = v.w;
      } else {
#pragma unroll
        for (int j = 0; j < 4; ++j)
          tile[rl][cq + j] = (c + j < C) ? in[(size_t)r * C + c + j] : 0.f;
      }
    }
  }
  __syncthreads();
  {
    const int c = t >> 2;
    const int rch = (t & 3) * 8;
    if (c0 + c < C) {
#pragma unroll
      for (int half = 0; half < 2; ++half) {
        int rb = rch + half * 32;
        uint4 o;
        o.x = pk(tile[rb + 0][c], tile[rb + 1][c]);
        o.y = pk(tile[rb + 2][c], tile[rb + 3][c]);
        o.z = pk(tile[rb + 4][c], tile[rb + 5][c]);
        o.w = pk(tile[rb + 6][c], tile[rb + 7][c]);
        *reinterpret_cast<uint4*>(&out[(size_t)(c0 + c) * R + r0 + rb]) = o;
      }
    }
  }
}

// fmap (B, R=CCH, C=HW) f32 -> (B, HW, CCH) bf16
__global__ __launch_bounds__(256) void k_transpose_cast(
    const float* __restrict__ in, u16* __restrict__ out, int R, int C) {
  const int b = blockIdx.z;
  transpose_tile(in + (size_t)b * R * C, out + (size_t)b * R * C, R, C,
                 blockIdx.x * 64, blockIdx.y * 64, threadIdx.x);
}

// both weight transposes in ONE launch: W1 (1024x1024) then W2 (1024x512)
__global__ __launch_bounds__(256) void k_transpose_w12(
    const float* __restrict__ W1, u16* __restrict__ W1b,
    const float* __restrict__ W2, u16* __restrict__ W2b) {
  const int bid = blockIdx.x;
  if (bid < 256) {  // W1: 16 x 16 tiles
    transpose_tile(W1, W1b, D1, D1, (bid & 15) * 64, (bid >> 4) * 64, threadIdx.x);
  } else {          // W2: 8 x 16 tiles
    const int b2 = bid - 256;
    transpose_tile(W2, W2b, D1, D2, (b2 & 7) * 64, (b2 >> 3) * 64, threadIdx.x);
  }
}

// ---------------- ROI align: dedup taps + static-variant dispatch ----------------
DEV void acc8v(uint4 v, float w, float* a) {
  a[0] = fmaf(w, bf2f((u16)(v.x & 0xffffu)), a[0]);
  a[1] = fmaf(w, bf2f((u16)(v.x >> 16)), a[1]);
  a[2] = fmaf(w, bf2f((u16)(v.y & 0xffffu)), a[2]);
  a[3] = fmaf(w, bf2f((u16)(v.y >> 16)), a[3]);
  a[4] = fmaf(w, bf2f((u16)(v.z & 0xffffu)), a[4]);
  a[5] = fmaf(w, bf2f((u16)(v.z >> 16)), a[5]);
  a[6] = fmaf(w, bf2f((u16)(v.w & 0xffffu)), a[6]);
  a[7] = fmaf(w, bf2f((u16)(v.w >> 16)), a[7]);
}

template <int YC, int XC>
DEV void bin_accum(const u16* bt, const int* yrow, const float* yw,
                   const int* xidx, const float* xw, float* a) {
  uint4 v[YC * XC];
#pragma unroll
  for (int jy = 0; jy < YC; ++jy)
#pragma unroll
    for (int jx = 0; jx < XC; ++jx)
      v[jy * XC + jx] =
          *reinterpret_cast<const uint4*>(bt + (size_t)(yrow[jy] + xidx[jx]) * CCH);
#pragma unroll
  for (int jy = 0; jy < YC; ++jy)
#pragma unroll
    for (int jx = 0; jx < XC; ++jx)
      acc8v(v[jy * XC + jx], yw[jy] * xw[jx], a);
}

__global__ __launch_bounds__(128) void k_roi_fast(
    const u16* __restrict__ fmT, const float* __restrict__ bboxes,
    const int* __restrict__ pfw, const int* __restrict__ pfh,
    u16* __restrict__ Aout) {
  const int r = blockIdx.x;   // roi 0..511
  const int py = blockIdx.y;  // bin row 0..6
  const int b = r >> 4;
  const int t = threadIdx.x;
  const int c0 = t * 8;

  __shared__ int s_cnt[2][7];
  __shared__ int s_idx[2][7][4];
  __shared__ float s_wgt[2][7][4];

  int axis = -1, p = 0;
  if (t < 7) { axis = 0; p = t; }
  else if (t >= 64 && t < 71) { axis = 1; p = t - 64; }
  if (axis >= 0) {
    float fwf = (float)pfw[0], fhf = (float)pfh[0];
    // reference: im_height = frame_width, im_width = frame_height
    float hs = (float)FHW / fwf;
    float wsc = (float)FHW / fhf;
    float v1 = bboxes[r * 4 + (axis == 0 ? 1 : 0)] * (axis == 0 ? hs : wsc);
    float v2 = bboxes[r * 4 + (axis == 0 ? 3 : 2)] * (axis == 0 ? hs : wsc);
    float ext = fmaxf(v2 - v1, 1.0f);
    int idx[4]; float wgt[4]; int cnt = 0;
#pragma unroll
    for (int j = 0; j < 2; ++j) {
      float g = (float)p + (j ? 0.75f : 0.25f);
      float coord = v1 + (ext / 7.0f) * g;
      float valid = (coord >= -1.0f && coord <= 50.0f) ? 1.0f : 0.0f;
      float cc = fmaxf(coord, 0.0f);
      int lo = (int)floorf(cc);
      bool edge = (lo >= FHW - 1);
      lo = min(lo, FHW - 1);
      int hi = min(lo + 1, FHW - 1);
      float l = edge ? 0.0f : (cc - (float)lo);
      float pr_i[2]; int pr_x[2];
      pr_x[0] = lo; pr_i[0] = valid * (1.0f - l);
      pr_x[1] = hi; pr_i[1] = valid * l;
#pragma unroll
      for (int e = 0; e < 2; ++e) {
        if (pr_i[e] != 0.0f) {
          bool found = false;
          for (int q = 0; q < cnt; ++q)
            if (idx[q] == pr_x[e]) { wgt[q] += pr_i[e]; found = true; }
          if (!found) { idx[cnt] = pr_x[e]; wgt[cnt] = pr_i[e]; ++cnt; }
        }
      }
    }
    s_cnt[axis][p] = cnt;
#pragma unroll
    for (int q = 0; q < 4; ++q) {
      s_idx[axis][p][q] = (q < cnt) ? idx[q] : 0;
      s_wgt[axis][p][q] = (q < cnt) ? wgt[q] : 0.0f;
    }
  }
  __syncthreads();

  const u16* bt = fmT + (size_t)b * HW * CCH + c0;

  const int ycnt = s_cnt[0][py];
  int yrow[3]; float yw[3];
#pragma unroll
  for (int q = 0; q < 3; ++q) {
    yrow[q] = s_idx[0][py][q] * FHW;
    yw[q] = s_wgt[0][py][q];
  }

  for (int px = 0; px < 7; ++px) {
    const int xcnt = s_cnt[1][px];
    int xidx[3]; float xw[3];
#pragma unroll
    for (int q = 0; q < 3; ++q) {
      xidx[q] = s_idx[1][px][q];
      xw[q] = s_wgt[1][px][q];
    }
    float a[8] = {};
    switch (ycnt * 4 + xcnt) {
      case 1 * 4 + 1: bin_accum<1, 1>(bt, yrow, yw, xidx, xw, a); break;
      case 1 * 4 + 2: bin_accum<1, 2>(bt, yrow, yw, xidx, xw, a); break;
      case 1 * 4 + 3: bin_accum<1, 3>(bt, yrow, yw, xidx, xw, a); break;
      case 2 * 4 + 1: bin_accum<2, 1>(bt, yrow, yw, xidx, xw, a); break;
      case 2 * 4 + 2: bin_accum<2, 2>(bt, yrow, yw, xidx, xw, a); break;
      case 2 * 4 + 3: bin_accum<2, 3>(bt, yrow, yw, xidx, xw, a); break;
      case 3 * 4 + 1: bin_accum<3, 1>(bt, yrow, yw, xidx, xw, a); break;
      case 3 * 4 + 2: bin_accum<3, 2>(bt, yrow, yw, xidx, xw, a); break;
      case 3 * 4 + 3: bin_accum<3, 3>(bt, yrow, yw, xidx, xw, a); break;
      default: break;  // cnt==0 on an axis -> bin all zeros
    }
    u16* dst = Aout + (size_t)(r * 49 + py * 7 + px) * CCH + c0;
    uint4 o;
    o.x = pk(a[0] * 0.25f, a[1] * 0.25f);
    o.y = pk(a[2] * 0.25f, a[3] * 0.25f);
    o.z = pk(a[4] * 0.25f, a[5] * 0.25f);
    o.w = pk(a[6] * 0.25f, a[7] * 0.25f);
    *reinterpret_cast<uint4*>(dst) = o;
  }
}

// ---------------- GEMM1 (m97 structure): H1 = relu(A @ W1b^T + b1) bf16 ------
template <int K, int N>
__global__ __launch_bounds__(256) void k_gemm(
    const u16* __restrict__ A, const u16* __restrict__ Bt,
    const float* __restrict__ bias, u16* __restrict__ Out) {
  __shared__ alignas(16) u16 As[128 * 32];
  __shared__ alignas(16) u16 Bs[128 * 32];
  const int t = threadIdx.x;
  const int lane = t & 63, w = t >> 6;
  const int wr = w >> 1, wc = w & 1;
  const int NT = N / 128;
  const int bid = blockIdx.x;
  const int chunk = (int)(gridDim.x >> 3);
  const int swz = (bid & 7) * chunk + (bid >> 3);
  const size_t m0 = (size_t)(swz / NT) * 128;
  const int n0 = (swz % NT) * 128;
  f32x4 acc[4][4] = {};
  const int srow = t >> 2;
  const int skc = (t & 3) * 8;
  for (int ks = 0; ks < K / 32; ++ks) {
    const int k0 = ks * 32;
    if (ks) __syncthreads();
    gl_lds16(A + (m0 + srow) * K + k0 + skc, &As[(size_t)t * 8]);
    gl_lds16(A + (m0 + 64 + srow) * K + k0 + skc, &As[(size_t)(t + 256) * 8]);
    gl_lds16(Bt + (size_t)(n0 + srow) * K + k0 + skc, &Bs[(size_t)t * 8]);
    gl_lds16(Bt + (size_t)(n0 + 64 + srow) * K + k0 + skc, &Bs[(size_t)(t + 256) * 8]);
    __syncthreads();
    const int koff = (lane >> 4) * 8;
    bf16x8 av[4], bv[4];
#pragma unroll
    for (int m = 0; m < 4; ++m)
      av[m] = *reinterpret_cast<const bf16x8*>(&As[(wr * 64 + m * 16 + (lane & 15)) * 32 + koff]);
#pragma unroll
    for (int n = 0; n < 4; ++n)
      bv[n] = *reinterpret_cast<const bf16x8*>(&Bs[(wc * 64 + n * 16 + (lane & 15)) * 32 + koff]);
#pragma unroll
    for (int m = 0; m < 4; ++m)
#pragma unroll
      for (int n = 0; n < 4; ++n)
        asm("v_mfma_f32_16x16x32_bf16 %0, %1, %2, %0"
            : "+v"(acc[m][n]) : "v"(av[m]), "v"(bv[n]));
  }
  asm volatile("s_nop 7\n\ts_nop 7\n\ts_nop 7" ::);
#pragma unroll
  for (int n = 0; n < 4; ++n) {
    int col = n0 + wc * 64 + n * 16 + (lane & 15);
    float bb = bias[col];
#pragma unroll
    for (int m = 0; m < 4; ++m) {
      size_t row0 = m0 + wr * 64 + m * 16 + (lane >> 4) * 4;
#pragma unroll
      for (int qq = 0; qq < 4; ++qq) {
        float v = fmaxf(acc[m][n][qq] + bb, 0.0f);
        Out[(row0 + qq) * N + col] = f2bf(v);
      }
    }
  }
}

// ------- GEMM2 + fused mean: feat[roi] += relu(H1 @ W2b^T + b2) / 49 --------
// Same m97 main loop (K=D1, N=D2); epilogue reduces the 128x128 tile into
// <=4 roi rows via LDS atomics, then ~2 global atomicAdds per feat element.
__global__ __launch_bounds__(256) void k_gemm2_fused(
    const u16* __restrict__ A, const u16* __restrict__ Bt,
    const float* __restrict__ bias, float* __restrict__ feat) {
  constexpr int K = D1, N = D2;
  __shared__ alignas(16) u16 As[128 * 32];
  __shared__ alignas(16) u16 Bs[128 * 32];
  __shared__ float sfeat[4][128];
  const int t = threadIdx.x;
  const int lane = t & 63, w = t >> 6;
  const int wr = w >> 1, wc = w & 1;
  const int NT = N / 128;
  const int bid = blockIdx.x;
  const int chunk = (int)(gridDim.x >> 3);
  const int swz = (bid & 7) * chunk + (bid >> 3);
  const size_t m0 = (size_t)(swz / NT) * 128;
  const int n0 = (swz % NT) * 128;
  f32x4 acc[4][4] = {};
  const int srow = t >> 2;
  const int skc = (t & 3) * 8;
  for (int ks = 0; ks < K / 32; ++ks) {
    const int k0 = ks * 32;
    if (ks) __syncthreads();
    gl_lds16(A + (m0 + srow) * K + k0 + skc, &As[(size_t)t * 8]);
    gl_lds16(A + (m0 + 64 + srow) * K + k0 + skc, &As[(size_t)(t + 256) * 8]);
    gl_lds16(Bt + (size_t)(n0 + srow) * K + k0 + skc, &Bs[(size_t)t * 8]);
    gl_lds16(Bt + (size_t)(n0 + 64 + srow) * K + k0 + skc, &Bs[(size_t)(t + 256) * 8]);
    __syncthreads();
    const int koff = (lane >> 4) * 8;
    bf16x8 av[4], bv[4];
#pragma unroll
    for (int m = 0; m < 4; ++m)
      av[m] = *reinterpret_cast<const bf16x8*>(&As[(wr * 64 + m * 16 + (lane & 15)) * 32 + koff]);
#pragma unroll
    for (int n = 0; n < 4; ++n)
      bv[n] = *reinterpret_cast<const bf16x8*>(&Bs[(wc * 64 + n * 16 + (lane & 15)) * 32 + koff]);
#pragma unroll
    for (int m = 0; m < 4; ++m)
#pragma unroll
      for (int n = 0; n < 4; ++n)
        asm("v_mfma_f32_16x16x32_bf16 %0, %1, %2, %0"
            : "+v"(acc[m][n]) : "v"(av[m]), "v"(bv[n]));
  }
  asm volatile("s_nop 7\n\ts_nop 7\n\ts_nop 7" ::);

  // zero the per-block roi accumulator
  __syncthreads();
  for (int idx = t; idx < 512; idx += 256) ((float*)sfeat)[idx] = 0.0f;
  __syncthreads();

  const int roi_base = (int)(m0 / 49);
#pragma unroll
  for (int n = 0; n < 4; ++n) {
    const int col = n0 + wc * 64 + n * 16 + (lane & 15);
    const int coll = wc * 64 + n * 16 + (lane & 15);
    const float bb = bias[col];
#pragma unroll
    for (int m = 0; m < 4; ++m) {
      const int row0 = (int)m0 + wr * 64 + m * 16 + (lane >> 4) * 4;
      // q-run of 4 consecutive rows: pre-merge runs within the same roi
      float run = 0.0f;
      int rl_prev = (row0) / 49 - roi_base;
#pragma unroll
      for (int qq = 0; qq < 4; ++qq) {
        const int rl = (row0 + qq) / 49 - roi_base;
        const float v = fmaxf(acc[m][n][qq] + bb, 0.0f);
        if (rl != rl_prev) {
          atomicAdd(&sfeat[rl_prev][coll], run);
          run = 0.0f;
          rl_prev = rl;
        }
        run += v;
      }
      atomicAdd(&sfeat[rl_prev][coll], run);
    }
  }
  __syncthreads();

  for (int idx = t; idx < 512; idx += 256) {
    const int rl = idx >> 7, cl = idx & 127;
    const int roi = roi_base + rl;
    if (roi < NROI) {
      const float s = sfeat[rl][cl];
      if (s != 0.0f) atomicAdd(&feat[(size_t)roi * D2 + n0 + cl], s * (1.0f / 49.0f));
    }
  }
}

// ---------------- zero feat (graph-capture-safe init) ----------------
__global__ __launch_bounds__(256) void k_zero(float4* __restrict__ p) {
  p[blockIdx.x * 256 + threadIdx.x] = float4{0.f, 0.f, 0.f, 0.f};
}

// ---------------- pair gather ----------------
__global__ __launch_bounds__(256) void k_pairs(
    const float* __restrict__ feat, const int* __restrict__ num_obj,
    const int* __restrict__ pairs, float* __restrict__ out) {
  int r = blockIdx.x;
  int b = r >> 6;
  int off = 0;
  for (int i = 0; i < b; ++i) off += num_obj[i];
  int g0 = off + pairs[r * 2 + 0];
  int g1 = off + pairs[r * 2 + 1];
  for (int c = threadIdx.x; c < D2; c += 256) {
    out[(size_t)r * D2 + c] = 0.5f * (feat[(size_t)g0 * D2 + c] + feat[(size_t)g1 * D2 + c]);
  }
}

extern "C" void kernel_launch(void* const* d_in, const int* in_sizes, int n_in,
                              void* d_out, int out_size, void* d_ws, size_t ws_size,
                              hipStream_t stream) {
  const float* fmap = (const float*)d_in[0];
  const float* bboxes = (const float*)d_in[1];
  const int* num_obj = (const int*)d_in[2];
  const int* obj_pairs = (const int*)d_in[3];
  const int* pfw = (const int*)d_in[5];
  const int* pfh = (const int*)d_in[6];
  const float* W1 = (const float*)d_in[7];
  const float* b1 = (const float*)d_in[8];
  const float* W2 = (const float*)d_in[9];
  const float* b2 = (const float*)d_in[10];
  float* out = (float*)d_out;

  const size_t SZ_FMT = (size_t)BB * HW * CCH * 2;
  const size_t SZ_A   = (size_t)MROWS * D1 * 2;
  const size_t SZ_H1  = (size_t)MROWS * D1 * 2;
  const size_t SZ_W1B = (size_t)D1 * D1 * 2;
  const size_t SZ_W2B = (size_t)D1 * D2 * 2;

  char* ws = (char*)d_ws;
  u16* fmT = (u16*)ws;
  u16* A   = (u16*)(ws + SZ_FMT);
  u16* H1  = (u16*)(ws + SZ_FMT + SZ_A);
  u16* W1b = (u16*)(ws + SZ_FMT + SZ_A + SZ_H1);
  u16* W2b = (u16*)(ws + SZ_FMT + SZ_A + SZ_H1 + SZ_W1B);
  float* feat = (float*)(ws + SZ_FMT + SZ_A + SZ_H1 + SZ_W1B + SZ_W2B);

  // feat zero-init (must precede k_gemm2_fused's atomics; same-stream ordering)
  k_zero<<<NROI * D2 / 1024, 256, 0, stream>>>((float4*)feat);

  // both weight transposes, one launch
  k_transpose_w12<<<384, 256, 0, stream>>>(W1, W1b, W2, W2b);

  // fmap (B, C=1024, HW=2500) -> (B, HW, C) bf16
  k_transpose_cast<<<dim3(40, 16, BB), 256, 0, stream>>>(fmap, fmT, CCH, HW);
  k_roi_fast<<<dim3(NROI, 7), 128, 0, stream>>>(fmT, bboxes, pfw, pfh, A);

  k_gemm<D1, D1><<<(MROWS / 128) * (D1 / 128), 256, 0, stream>>>(A, W1b, b1, H1);
  k_gemm2_fused<<<(MROWS / 128) * (D2 / 128), 256, 0, stream>>>(H1, W2b, b2, feat);
  k_pairs<<<BB * NREL, 256, 0, stream>>>(feat, num_obj, obj_pairs, out);
}

// Round 8
// 257.742 us; speedup vs baseline: 1.0902x; 1.0902x over previous
//
#include <hip/hip_runtime.h>

#define DEV __device__ __forceinline__

typedef unsigned short u16;
typedef short bf16x8 __attribute__((ext_vector_type(8)));
typedef float f32x4 __attribute__((ext_vector_type(4)));

// ---- problem constants (match reference) ----
#define BB    32
#define NOBJ  16
#define NREL  64
#define CCH   1024
#define FHW   50
#define HW    2500      // 50*50
#define NROI  512       // BB*NOBJ
#define MROWS 25088     // NROI*49  (= 196*128)
#define D1    1024
#define D2    512

DEV u16 f2bf(float f) {
  unsigned u = __float_as_uint(f);
  unsigned r = (u + 0x7FFFu + ((u >> 16) & 1u)) >> 16;
  return (u16)r;
}
DEV float bf2f(u16 h) { return __uint_as_float((unsigned)h << 16); }
DEV unsigned pk(float lo, float hi) { return (unsigned)f2bf(lo) | ((unsigned)f2bf(hi) << 16); }

using gvoid = __attribute__((address_space(1))) const void;
using svoid = __attribute__((address_space(3))) void;
DEV void gl_lds16(const void* g, void* s) {
  __builtin_amdgcn_global_load_lds((gvoid*)g, (svoid*)s, 16, 0, 0);
}

// ---------------- shared 64x64 transpose tile (f32 -> bf16) ----------------
// in: (R, C) f32 ; writes out[(c0+c)*R + r0+r] bf16 for the 64x64 tile.
DEV void transpose_tile(const float* __restrict__ in, u16* __restrict__ out,
                        int R, int C, int c0, int r0, int t) {
  __shared__ float tile[64][65];
  {
    const int rr = t >> 4;
    const int cq = (t & 15) * 4;
#pragma unroll
    for (int it = 0; it < 4; ++it) {
      int rl = rr + it * 16;
      int r = r0 + rl;
      int c = c0 + cq;
      if (c + 3 < C) {
        float4 v = *reinterpret_cast<const float4*>(&in[(size_t)r * C + c]);
        tile[rl][cq + 0] = v.x; tile[rl][cq + 1] = v.y;
        tile[rl][cq + 2] = v.z; tile[rl][cq + 3] = v.w;
      } else {
#pragma unroll
        for (int j = 0; j < 4; ++j)
          tile[rl][cq + j] = (c + j < C) ? in[(size_t)r * C + c + j] : 0.f;
      }
    }
  }
  __syncthreads();
  {
    const int c = t >> 2;
    const int rch = (t & 3) * 8;
    if (c0 + c < C) {
#pragma unroll
      for (int half = 0; half < 2; ++half) {
        int rb = rch + half * 32;
        uint4 o;
        o.x = pk(tile[rb + 0][c], tile[rb + 1][c]);
        o.y = pk(tile[rb + 2][c], tile[rb + 3][c]);
        o.z = pk(tile[rb + 4][c], tile[rb + 5][c]);
        o.w = pk(tile[rb + 6][c], tile[rb + 7][c]);
        *reinterpret_cast<uint4*>(&out[(size_t)(c0 + c) * R + r0 + rb]) = o;
      }
    }
  }
}

// ONE launch for all transposes: W1 (16x16 tiles), W2 (8x16 tiles),
// fmap (B * 40x16 tiles): (B, C=1024, HW=2500) f32 -> (B, HW, C) bf16
__global__ __launch_bounds__(256) void k_transpose_all(
    const float* __restrict__ W1, u16* __restrict__ W1b,
    const float* __restrict__ W2, u16* __restrict__ W2b,
    const float* __restrict__ fmap, u16* __restrict__ fmT) {
  const int bid = blockIdx.x;
  const int t = threadIdx.x;
  if (bid < 256) {          // W1: (D1 x D1)
    transpose_tile(W1, W1b, D1, D1, (bid & 15) * 64, (bid >> 4) * 64, t);
  } else if (bid < 384) {   // W2: (D1 x D2)
    const int b2 = bid - 256;
    transpose_tile(W2, W2b, D1, D2, (b2 & 7) * 64, (b2 >> 3) * 64, t);
  } else {                  // fmap: per batch 40 col-tiles x 16 row-tiles
    const int f = bid - 384;
    const int b = f / 640;
    const int rem = f - b * 640;
    const int cx = rem % 40, ry = rem / 40;
    transpose_tile(fmap + (size_t)b * CCH * HW, fmT + (size_t)b * CCH * HW,
                   CCH, HW, cx * 64, ry * 64, t);
  }
}

// ---------------- ROI align: dedup taps + static-variant dispatch ----------------
DEV void acc8v(uint4 v, float w, float* a) {
  a[0] = fmaf(w, bf2f((u16)(v.x & 0xffffu)), a[0]);
  a[1] = fmaf(w, bf2f((u16)(v.x >> 16)), a[1]);
  a[2] = fmaf(w, bf2f((u16)(v.y & 0xffffu)), a[2]);
  a[3] = fmaf(w, bf2f((u16)(v.y >> 16)), a[3]);
  a[4] = fmaf(w, bf2f((u16)(v.z & 0xffffu)), a[4]);
  a[5] = fmaf(w, bf2f((u16)(v.z >> 16)), a[5]);
  a[6] = fmaf(w, bf2f((u16)(v.w & 0xffffu)), a[6]);
  a[7] = fmaf(w, bf2f((u16)(v.w >> 16)), a[7]);
}

template <int YC, int XC>
DEV void bin_accum(const u16* bt, const int* yrow, const float* yw,
                   const int* xidx, const float* xw, float* a) {
  uint4 v[YC * XC];
#pragma unroll
  for (int jy = 0; jy < YC; ++jy)
#pragma unroll
    for (int jx = 0; jx < XC; ++jx)
      v[jy * XC + jx] =
          *reinterpret_cast<const uint4*>(bt + (size_t)(yrow[jy] + xidx[jx]) * CCH);
#pragma unroll
  for (int jy = 0; jy < YC; ++jy)
#pragma unroll
    for (int jx = 0; jx < XC; ++jx)
      acc8v(v[jy * XC + jx], yw[jy] * xw[jx], a);
}

__global__ __launch_bounds__(128) void k_roi_fast(
    const u16* __restrict__ fmT, const float* __restrict__ bboxes,
    const int* __restrict__ pfw, const int* __restrict__ pfh,
    u16* __restrict__ Aout) {
  const int r = blockIdx.x;   // roi 0..511
  const int py = blockIdx.y;  // bin row 0..6
  const int b = r >> 4;
  const int t = threadIdx.x;
  const int c0 = t * 8;

  __shared__ int s_cnt[2][7];
  __shared__ int s_idx[2][7][4];
  __shared__ float s_wgt[2][7][4];

  int axis = -1, p = 0;
  if (t < 7) { axis = 0; p = t; }
  else if (t >= 64 && t < 71) { axis = 1; p = t - 64; }
  if (axis >= 0) {
    float fwf = (float)pfw[0], fhf = (float)pfh[0];
    // reference: im_height = frame_width, im_width = frame_height
    float hs = (float)FHW / fwf;
    float wsc = (float)FHW / fhf;
    float v1 = bboxes[r * 4 + (axis == 0 ? 1 : 0)] * (axis == 0 ? hs : wsc);
    float v2 = bboxes[r * 4 + (axis == 0 ? 3 : 2)] * (axis == 0 ? hs : wsc);
    float ext = fmaxf(v2 - v1, 1.0f);
    int idx[4]; float wgt[4]; int cnt = 0;
#pragma unroll
    for (int j = 0; j < 2; ++j) {
      float g = (float)p + (j ? 0.75f : 0.25f);
      float coord = v1 + (ext / 7.0f) * g;
      float valid = (coord >= -1.0f && coord <= 50.0f) ? 1.0f : 0.0f;
      float cc = fmaxf(coord, 0.0f);
      int lo = (int)floorf(cc);
      bool edge = (lo >= FHW - 1);
      lo = min(lo, FHW - 1);
      int hi = min(lo + 1, FHW - 1);
      float l = edge ? 0.0f : (cc - (float)lo);
      float pr_i[2]; int pr_x[2];
      pr_x[0] = lo; pr_i[0] = valid * (1.0f - l);
      pr_x[1] = hi; pr_i[1] = valid * l;
#pragma unroll
      for (int e = 0; e < 2; ++e) {
        if (pr_i[e] != 0.0f) {
          bool found = false;
          for (int q = 0; q < cnt; ++q)
            if (idx[q] == pr_x[e]) { wgt[q] += pr_i[e]; found = true; }
          if (!found) { idx[cnt] = pr_x[e]; wgt[cnt] = pr_i[e]; ++cnt; }
        }
      }
    }
    s_cnt[axis][p] = cnt;
#pragma unroll
    for (int q = 0; q < 4; ++q) {
      s_idx[axis][p][q] = (q < cnt) ? idx[q] : 0;
      s_wgt[axis][p][q] = (q < cnt) ? wgt[q] : 0.0f;
    }
  }
  __syncthreads();

  const u16* bt = fmT + (size_t)b * HW * CCH + c0;

  const int ycnt = s_cnt[0][py];
  int yrow[3]; float yw[3];
#pragma unroll
  for (int q = 0; q < 3; ++q) {
    yrow[q] = s_idx[0][py][q] * FHW;
    yw[q] = s_wgt[0][py][q];
  }

  for (int px = 0; px < 7; ++px) {
    const int xcnt = s_cnt[1][px];
    int xidx[3]; float xw[3];
#pragma unroll
    for (int q = 0; q < 3; ++q) {
      xidx[q] = s_idx[1][px][q];
      xw[q] = s_wgt[1][px][q];
    }
    float a[8] = {};
    switch (ycnt * 4 + xcnt) {
      case 1 * 4 + 1: bin_accum<1, 1>(bt, yrow, yw, xidx, xw, a); break;
      case 1 * 4 + 2: bin_accum<1, 2>(bt, yrow, yw, xidx, xw, a); break;
      case 1 * 4 + 3: bin_accum<1, 3>(bt, yrow, yw, xidx, xw, a); break;
      case 2 * 4 + 1: bin_accum<2, 1>(bt, yrow, yw, xidx, xw, a); break;
      case 2 * 4 + 2: bin_accum<2, 2>(bt, yrow, yw, xidx, xw, a); break;
      case 2 * 4 + 3: bin_accum<2, 3>(bt, yrow, yw, xidx, xw, a); break;
      case 3 * 4 + 1: bin_accum<3, 1>(bt, yrow, yw, xidx, xw, a); break;
      case 3 * 4 + 2: bin_accum<3, 2>(bt, yrow, yw, xidx, xw, a); break;
      case 3 * 4 + 3: bin_accum<3, 3>(bt, yrow, yw, xidx, xw, a); break;
      default: break;  // cnt==0 on an axis -> bin all zeros
    }
    u16* dst = Aout + (size_t)(r * 49 + py * 7 + px) * CCH + c0;
    uint4 o;
    o.x = pk(a[0] * 0.25f, a[1] * 0.25f);
    o.y = pk(a[2] * 0.25f, a[3] * 0.25f);
    o.z = pk(a[4] * 0.25f, a[5] * 0.25f);
    o.w = pk(a[6] * 0.25f, a[7] * 0.25f);
    *reinterpret_cast<uint4*>(dst) = o;
  }
}

// ---------------- GEMM (m97 structure, proven): Out = relu(A @ Bt^T + bias) ---
// A: (M,K) bf16 row-major.  Bt: (N,K) bf16 row-major.
// 128x128 tile, BK=32, 4 waves (2x2), 4x4 16x16 frags/wave.
// 1D grid, XCD-chunked swizzle (gridDim.x % 8 == 0), n-tile fastest.
template <int K, int N, int OBF>
__global__ __launch_bounds__(256) void k_gemm(
    const u16* __restrict__ A, const u16* __restrict__ Bt,
    const float* __restrict__ bias, void* __restrict__ Out) {
  __shared__ alignas(16) u16 As[128 * 32];
  __shared__ alignas(16) u16 Bs[128 * 32];
  const int t = threadIdx.x;
  const int lane = t & 63, w = t >> 6;
  const int wr = w >> 1, wc = w & 1;
  const int NT = N / 128;
  const int bid = blockIdx.x;
  const int chunk = (int)(gridDim.x >> 3);
  const int swz = (bid & 7) * chunk + (bid >> 3);
  const size_t m0 = (size_t)(swz / NT) * 128;
  const int n0 = (swz % NT) * 128;
  f32x4 acc[4][4] = {};
  const int srow = t >> 2;
  const int skc = (t & 3) * 8;
  for (int ks = 0; ks < K / 32; ++ks) {
    const int k0 = ks * 32;
    if (ks) __syncthreads();
    gl_lds16(A + (m0 + srow) * K + k0 + skc, &As[(size_t)t * 8]);
    gl_lds16(A + (m0 + 64 + srow) * K + k0 + skc, &As[(size_t)(t + 256) * 8]);
    gl_lds16(Bt + (size_t)(n0 + srow) * K + k0 + skc, &Bs[(size_t)t * 8]);
    gl_lds16(Bt + (size_t)(n0 + 64 + srow) * K + k0 + skc, &Bs[(size_t)(t + 256) * 8]);
    __syncthreads();
    const int koff = (lane >> 4) * 8;
    bf16x8 av[4], bv[4];
#pragma unroll
    for (int m = 0; m < 4; ++m)
      av[m] = *reinterpret_cast<const bf16x8*>(&As[(wr * 64 + m * 16 + (lane & 15)) * 32 + koff]);
#pragma unroll
    for (int n = 0; n < 4; ++n)
      bv[n] = *reinterpret_cast<const bf16x8*>(&Bs[(wc * 64 + n * 16 + (lane & 15)) * 32 + koff]);
#pragma unroll
    for (int m = 0; m < 4; ++m)
#pragma unroll
      for (int n = 0; n < 4; ++n)
        asm("v_mfma_f32_16x16x32_bf16 %0, %1, %2, %0"
            : "+v"(acc[m][n]) : "v"(av[m]), "v"(bv[n]));
  }
  asm volatile("s_nop 7\n\ts_nop 7\n\ts_nop 7" ::);
#pragma unroll
  for (int n = 0; n < 4; ++n) {
    int col = n0 + wc * 64 + n * 16 + (lane & 15);
    float bb = bias[col];
#pragma unroll
    for (int m = 0; m < 4; ++m) {
      size_t row0 = m0 + wr * 64 + m * 16 + (lane >> 4) * 4;
#pragma unroll
      for (int qq = 0; qq < 4; ++qq) {
        float v = fmaxf(acc[m][n][qq] + bb, 0.0f);
        if (OBF) ((u16*)Out)[(row0 + qq) * N + col] = f2bf(v);
        else     ((float*)Out)[(row0 + qq) * N + col] = v;
      }
    }
  }
}

// ---------------- mean over 49 bins (bf16 input) ----------------
__global__ __launch_bounds__(256) void k_mean(const u16* __restrict__ H2,
                                              float* __restrict__ feat) {
  const int r = blockIdx.x;
  const int c = threadIdx.x * 2;
  float s0 = 0.f, s1 = 0.f;
#pragma unroll
  for (int qq = 0; qq < 49; ++qq) {
    unsigned v = *reinterpret_cast<const unsigned*>(&H2[((size_t)r * 49 + qq) * D2 + c]);
    s0 += bf2f((u16)(v & 0xffffu));
    s1 += bf2f((u16)(v >> 16));
  }
  feat[(size_t)r * D2 + c] = s0 * (1.0f / 49.0f);
  feat[(size_t)r * D2 + c + 1] = s1 * (1.0f / 49.0f);
}

// ---------------- pair gather ----------------
__global__ __launch_bounds__(256) void k_pairs(
    const float* __restrict__ feat, const int* __restrict__ num_obj,
    const int* __restrict__ pairs, float* __restrict__ out) {
  int r = blockIdx.x;
  int b = r >> 6;
  int off = 0;
  for (int i = 0; i < b; ++i) off += num_obj[i];
  int g0 = off + pairs[r * 2 + 0];
  int g1 = off + pairs[r * 2 + 1];
  for (int c = threadIdx.x; c < D2; c += 256) {
    out[(size_t)r * D2 + c] = 0.5f * (feat[(size_t)g0 * D2 + c] + feat[(size_t)g1 * D2 + c]);
  }
}

extern "C" void kernel_launch(void* const* d_in, const int* in_sizes, int n_in,
                              void* d_out, int out_size, void* d_ws, size_t ws_size,
                              hipStream_t stream) {
  const float* fmap = (const float*)d_in[0];
  const float* bboxes = (const float*)d_in[1];
  const int* num_obj = (const int*)d_in[2];
  const int* obj_pairs = (const int*)d_in[3];
  const int* pfw = (const int*)d_in[5];
  const int* pfh = (const int*)d_in[6];
  const float* W1 = (const float*)d_in[7];
  const float* b1 = (const float*)d_in[8];
  const float* W2 = (const float*)d_in[9];
  const float* b2 = (const float*)d_in[10];
  float* out = (float*)d_out;

  const size_t SZ_FMT = (size_t)BB * HW * CCH * 2;
  const size_t SZ_A   = (size_t)MROWS * D1 * 2;
  const size_t SZ_H1  = (size_t)MROWS * D1 * 2;
  const size_t SZ_W1B = (size_t)D1 * D1 * 2;
  const size_t SZ_W2B = (size_t)D1 * D2 * 2;

  char* ws = (char*)d_ws;
  u16* fmT = (u16*)ws;
  u16* A   = (u16*)(ws + SZ_FMT);
  u16* H1  = (u16*)(ws + SZ_FMT + SZ_A);
  u16* W1b = (u16*)(ws + SZ_FMT + SZ_A + SZ_H1);
  u16* W2b = (u16*)(ws + SZ_FMT + SZ_A + SZ_H1 + SZ_W1B);
  float* feat = (float*)(ws + SZ_FMT + SZ_A + SZ_H1 + SZ_W1B + SZ_W2B);
  u16* H2b = fmT;  // fmT dead after ROI align

  // all transposes in ONE launch: W1 (256 tiles) + W2 (128) + fmap (32*640)
  k_transpose_all<<<384 + BB * 640, 256, 0, stream>>>(W1, W1b, W2, W2b, fmap, fmT);

  k_roi_fast<<<dim3(NROI, 7), 128, 0, stream>>>(fmT, bboxes, pfw, pfh, A);

  k_gemm<D1, D1, 1><<<(MROWS / 128) * (D1 / 128), 256, 0, stream>>>(A, W1b, b1, (void*)H1);
  k_gemm<D1, D2, 1><<<(MROWS / 128) * (D2 / 128), 256, 0, stream>>>(H1, W2b, b2, (void*)H2b);
  k_mean<<<NROI, 256, 0, stream>>>(H2b, feat);
  k_pairs<<<BB * NREL, 256, 0, stream>>>(feat, num_obj, obj_pairs, out);
}

// Round 9
// 252.069 us; speedup vs baseline: 1.1148x; 1.0225x over previous
//
#include <hip/hip_runtime.h>

#define DEV __device__ __forceinline__

typedef unsigned short u16;
typedef short bf16x8 __attribute__((ext_vector_type(8)));
typedef float f32x4 __attribute__((ext_vector_type(4)));

// ---- problem constants (match reference) ----
#define BB    32
#define NOBJ  16
#define NREL  64
#define CCH   1024
#define FHW   50
#define HW    2500      // 50*50
#define NROI  512       // BB*NOBJ
#define MROWS 25088     // NROI*49  (= 196*128)
#define D1    1024
#define D2    512

DEV u16 f2bf(float f) {
  unsigned u = __float_as_uint(f);
  unsigned r = (u + 0x7FFFu + ((u >> 16) & 1u)) >> 16;
  return (u16)r;
}
DEV float bf2f(u16 h) { return __uint_as_float((unsigned)h << 16); }
DEV unsigned pk(float lo, float hi) { return (unsigned)f2bf(lo) | ((unsigned)f2bf(hi) << 16); }

using gvoid = __attribute__((address_space(1))) const void;
using svoid = __attribute__((address_space(3))) void;
DEV void gl_lds16(const void* g, void* s) {
  __builtin_amdgcn_global_load_lds((gvoid*)g, (svoid*)s, 16, 0, 0);
}

// ---------------- shared 64x64 transpose tile (f32 -> bf16) ----------------
// in: (R, C) f32 ; writes out[(c0+c)*R + r0+r] bf16 for the 64x64 tile.
DEV void transpose_tile(const float* __restrict__ in, u16* __restrict__ out,
                        int R, int C, int c0, int r0, int t) {
  __shared__ float tile[64][65];
  {
    const int rr = t >> 4;
    const int cq = (t & 15) * 4;
#pragma unroll
    for (int it = 0; it < 4; ++it) {
      int rl = rr + it * 16;
      int r = r0 + rl;
      int c = c0 + cq;
      if (c + 3 < C) {
        float4 v = *reinterpret_cast<const float4*>(&in[(size_t)r * C + c]);
        tile[rl][cq + 0] = v.x; tile[rl][cq + 1] = v.y;
        tile[rl][cq + 2] = v.z; tile[rl][cq + 3] = v.w;
      } else {
#pragma unroll
        for (int j = 0; j < 4; ++j)
          tile[rl][cq + j] = (c + j < C) ? in[(size_t)r * C + c + j] : 0.f;
      }
    }
  }
  __syncthreads();
  {
    const int c = t >> 2;
    const int rch = (t & 3) * 8;
    if (c0 + c < C) {
#pragma unroll
      for (int half = 0; half < 2; ++half) {
        int rb = rch + half * 32;
        uint4 o;
        o.x = pk(tile[rb + 0][c], tile[rb + 1][c]);
        o.y = pk(tile[rb + 2][c], tile[rb + 3][c]);
        o.z = pk(tile[rb + 4][c], tile[rb + 5][c]);
        o.w = pk(tile[rb + 6][c], tile[rb + 7][c]);
        *reinterpret_cast<uint4*>(&out[(size_t)(c0 + c) * R + r0 + rb]) = o;
      }
    }
  }
}

// ONE launch for all transposes: W1 (16x16 tiles), W2 (8x16 tiles),
// fmap (B * 40x16 tiles): (B, C=1024, HW=2500) f32 -> (B, HW, C) bf16
__global__ __launch_bounds__(256) void k_transpose_all(
    const float* __restrict__ W1, u16* __restrict__ W1b,
    const float* __restrict__ W2, u16* __restrict__ W2b,
    const float* __restrict__ fmap, u16* __restrict__ fmT) {
  const int bid = blockIdx.x;
  const int t = threadIdx.x;
  if (bid < 256) {          // W1: (D1 x D1)
    transpose_tile(W1, W1b, D1, D1, (bid & 15) * 64, (bid >> 4) * 64, t);
  } else if (bid < 384) {   // W2: (D1 x D2)
    const int b2 = bid - 256;
    transpose_tile(W2, W2b, D1, D2, (b2 & 7) * 64, (b2 >> 3) * 64, t);
  } else {                  // fmap: per batch 40 col-tiles x 16 row-tiles
    const int f = bid - 384;
    const int b = f / 640;
    const int rem = f - b * 640;
    const int cx = rem % 40, ry = rem / 40;
    transpose_tile(fmap + (size_t)b * CCH * HW, fmT + (size_t)b * CCH * HW,
                   CCH, HW, cx * 64, ry * 64, t);
  }
}

// ---------------- ROI align: dedup taps + static-variant dispatch ----------------
DEV void acc8v(uint4 v, float w, float* a) {
  a[0] = fmaf(w, bf2f((u16)(v.x & 0xffffu)), a[0]);
  a[1] = fmaf(w, bf2f((u16)(v.x >> 16)), a[1]);
  a[2] = fmaf(w, bf2f((u16)(v.y & 0xffffu)), a[2]);
  a[3] = fmaf(w, bf2f((u16)(v.y >> 16)), a[3]);
  a[4] = fmaf(w, bf2f((u16)(v.z & 0xffffu)), a[4]);
  a[5] = fmaf(w, bf2f((u16)(v.z >> 16)), a[5]);
  a[6] = fmaf(w, bf2f((u16)(v.w & 0xffffu)), a[6]);
  a[7] = fmaf(w, bf2f((u16)(v.w >> 16)), a[7]);
}

template <int YC, int XC>
DEV void bin_accum(const u16* bt, const int* yrow, const float* yw,
                   const int* xidx, const float* xw, float* a) {
  uint4 v[YC * XC];
#pragma unroll
  for (int jy = 0; jy < YC; ++jy)
#pragma unroll
    for (int jx = 0; jx < XC; ++jx)
      v[jy * XC + jx] =
          *reinterpret_cast<const uint4*>(bt + (size_t)(yrow[jy] + xidx[jx]) * CCH);
#pragma unroll
  for (int jy = 0; jy < YC; ++jy)
#pragma unroll
    for (int jx = 0; jx < XC; ++jx)
      acc8v(v[jy * XC + jx], yw[jy] * xw[jx], a);
}

__global__ __launch_bounds__(128) void k_roi_fast(
    const u16* __restrict__ fmT, const float* __restrict__ bboxes,
    const int* __restrict__ pfw, const int* __restrict__ pfh,
    u16* __restrict__ Aout) {
  const int r = blockIdx.x;   // roi 0..511
  const int py = blockIdx.y;  // bin row 0..6
  const int b = r >> 4;
  const int t = threadIdx.x;
  const int c0 = t * 8;

  __shared__ int s_cnt[2][7];
  __shared__ int s_idx[2][7][4];
  __shared__ float s_wgt[2][7][4];

  int axis = -1, p = 0;
  if (t < 7) { axis = 0; p = t; }
  else if (t >= 64 && t < 71) { axis = 1; p = t - 64; }
  if (axis >= 0) {
    float fwf = (float)pfw[0], fhf = (float)pfh[0];
    // reference: im_height = frame_width, im_width = frame_height
    float hs = (float)FHW / fwf;
    float wsc = (float)FHW / fhf;
    float v1 = bboxes[r * 4 + (axis == 0 ? 1 : 0)] * (axis == 0 ? hs : wsc);
    float v2 = bboxes[r * 4 + (axis == 0 ? 3 : 2)] * (axis == 0 ? hs : wsc);
    float ext = fmaxf(v2 - v1, 1.0f);
    int idx[4]; float wgt[4]; int cnt = 0;
#pragma unroll
    for (int j = 0; j < 2; ++j) {
      float g = (float)p + (j ? 0.75f : 0.25f);
      float coord = v1 + (ext / 7.0f) * g;
      float valid = (coord >= -1.0f && coord <= 50.0f) ? 1.0f : 0.0f;
      float cc = fmaxf(coord, 0.0f);
      int lo = (int)floorf(cc);
      bool edge = (lo >= FHW - 1);
      lo = min(lo, FHW - 1);
      int hi = min(lo + 1, FHW - 1);
      float l = edge ? 0.0f : (cc - (float)lo);
      float pr_i[2]; int pr_x[2];
      pr_x[0] = lo; pr_i[0] = valid * (1.0f - l);
      pr_x[1] = hi; pr_i[1] = valid * l;
#pragma unroll
      for (int e = 0; e < 2; ++e) {
        if (pr_i[e] != 0.0f) {
          bool found = false;
          for (int q = 0; q < cnt; ++q)
            if (idx[q] == pr_x[e]) { wgt[q] += pr_i[e]; found = true; }
          if (!found) { idx[cnt] = pr_x[e]; wgt[cnt] = pr_i[e]; ++cnt; }
        }
      }
    }
    s_cnt[axis][p] = cnt;
#pragma unroll
    for (int q = 0; q < 4; ++q) {
      s_idx[axis][p][q] = (q < cnt) ? idx[q] : 0;
      s_wgt[axis][p][q] = (q < cnt) ? wgt[q] : 0.0f;
    }
  }
  __syncthreads();

  const u16* bt = fmT + (size_t)b * HW * CCH + c0;

  const int ycnt = s_cnt[0][py];
  int yrow[3]; float yw[3];
#pragma unroll
  for (int q = 0; q < 3; ++q) {
    yrow[q] = s_idx[0][py][q] * FHW;
    yw[q] = s_wgt[0][py][q];
  }

  for (int px = 0; px < 7; ++px) {
    const int xcnt = s_cnt[1][px];
    int xidx[3]; float xw[3];
#pragma unroll
    for (int q = 0; q < 3; ++q) {
      xidx[q] = s_idx[1][px][q];
      xw[q] = s_wgt[1][px][q];
    }
    float a[8] = {};
    switch (ycnt * 4 + xcnt) {
      case 1 * 4 + 1: bin_accum<1, 1>(bt, yrow, yw, xidx, xw, a); break;
      case 1 * 4 + 2: bin_accum<1, 2>(bt, yrow, yw, xidx, xw, a); break;
      case 1 * 4 + 3: bin_accum<1, 3>(bt, yrow, yw, xidx, xw, a); break;
      case 2 * 4 + 1: bin_accum<2, 1>(bt, yrow, yw, xidx, xw, a); break;
      case 2 * 4 + 2: bin_accum<2, 2>(bt, yrow, yw, xidx, xw, a); break;
      case 2 * 4 + 3: bin_accum<2, 3>(bt, yrow, yw, xidx, xw, a); break;
      case 3 * 4 + 1: bin_accum<3, 1>(bt, yrow, yw, xidx, xw, a); break;
      case 3 * 4 + 2: bin_accum<3, 2>(bt, yrow, yw, xidx, xw, a); break;
      case 3 * 4 + 3: bin_accum<3, 3>(bt, yrow, yw, xidx, xw, a); break;
      default: break;  // cnt==0 on an axis -> bin all zeros
    }
    u16* dst = Aout + (size_t)(r * 49 + py * 7 + px) * CCH + c0;
    uint4 o;
    o.x = pk(a[0] * 0.25f, a[1] * 0.25f);
    o.y = pk(a[2] * 0.25f, a[3] * 0.25f);
    o.z = pk(a[4] * 0.25f, a[5] * 0.25f);
    o.w = pk(a[6] * 0.25f, a[7] * 0.25f);
    *reinterpret_cast<uint4*>(dst) = o;
  }
}

// ---------------- GEMM: Out = relu(A @ Bt^T + bias), BK=64 + chunk swizzle ---
// A: (M,K) bf16 row-major.  Bt: (N,K) bf16 row-major.
// 128x128 tile, BK=64 (half the barriers of BK=32), 4 waves (2x2), 4x4 frags.
// LDS [128][64] bf16 per operand; row stride = 128 B = 32 banks, so fragment
// reads need a swizzle: 16B-chunk XOR  phys_chunk = chunk ^ (row & 7).
// Applied BOTH sides (rule #21): linear global_load_lds dest + inverse-swizzled
// global source + swizzled ds_read.  K-accumulation order identical to BK=32
// (ks=0 then ks=1) -> bit-identical output.
template <int K, int N, int OBF>
__global__ __launch_bounds__(256) void k_gemm(
    const u16* __restrict__ A, const u16* __restrict__ Bt,
    const float* __restrict__ bias, void* __restrict__ Out) {
  __shared__ alignas(16) u16 As[128 * 64];
  __shared__ alignas(16) u16 Bs[128 * 64];
  const int t = threadIdx.x;
  const int lane = t & 63, w = t >> 6;
  const int wr = w >> 1, wc = w & 1;
  const int NT = N / 128;
  const int bid = blockIdx.x;
  const int chunk = (int)(gridDim.x >> 3);
  const int swz = (bid & 7) * chunk + (bid >> 3);
  const size_t m0 = (size_t)(swz / NT) * 128;
  const int n0 = (swz % NT) * 128;
  f32x4 acc[4][4] = {};

  // staging: thread t stages chunks i = t + 256*j (j=0..3) for A and B.
  // chunk i -> row = i>>3, logical col-chunk = i&7, source chunk = (i&7)^(row&7)
  int srow[4], scol[4];
#pragma unroll
  for (int j = 0; j < 4; ++j) {
    const int i = t + 256 * j;
    srow[j] = i >> 3;
    scol[j] = ((i & 7) ^ (srow[j] & 7)) * 8;  // element offset within row
  }

  for (int kt = 0; kt < K / 64; ++kt) {
    const int k0 = kt * 64;
    if (kt) __syncthreads();
#pragma unroll
    for (int j = 0; j < 4; ++j) {
      gl_lds16(A + (m0 + srow[j]) * K + k0 + scol[j], &As[(size_t)(t + 256 * j) * 8]);
      gl_lds16(Bt + (size_t)(n0 + srow[j]) * K + k0 + scol[j], &Bs[(size_t)(t + 256 * j) * 8]);
    }
    __syncthreads();

    bf16x8 av[2][4], bv[2][4];
#pragma unroll
    for (int ks = 0; ks < 2; ++ks) {
      const int lchunk = ks * 4 + (lane >> 4);  // logical 16B chunk in row
#pragma unroll
      for (int m = 0; m < 4; ++m) {
        const int row = wr * 64 + m * 16 + (lane & 15);
        av[ks][m] = *reinterpret_cast<const bf16x8*>(
            &As[row * 64 + (lchunk ^ (row & 7)) * 8]);
      }
#pragma unroll
      for (int n = 0; n < 4; ++n) {
        const int row = wc * 64 + n * 16 + (lane & 15);
        bv[ks][n] = *reinterpret_cast<const bf16x8*>(
            &Bs[row * 64 + (lchunk ^ (row & 7)) * 8]);
      }
    }
#pragma unroll
    for (int ks = 0; ks < 2; ++ks)
#pragma unroll
      for (int m = 0; m < 4; ++m)
#pragma unroll
        for (int n = 0; n < 4; ++n)
          asm("v_mfma_f32_16x16x32_bf16 %0, %1, %2, %0"
              : "+v"(acc[m][n]) : "v"(av[ks][m]), "v"(bv[ks][n]));
  }
  asm volatile("s_nop 7\n\ts_nop 7\n\ts_nop 7" ::);
#pragma unroll
  for (int n = 0; n < 4; ++n) {
    int col = n0 + wc * 64 + n * 16 + (lane & 15);
    float bb = bias[col];
#pragma unroll
    for (int m = 0; m < 4; ++m) {
      size_t row0 = m0 + wr * 64 + m * 16 + (lane >> 4) * 4;
#pragma unroll
      for (int qq = 0; qq < 4; ++qq) {
        float v = fmaxf(acc[m][n][qq] + bb, 0.0f);
        if (OBF) ((u16*)Out)[(row0 + qq) * N + col] = f2bf(v);
        else     ((float*)Out)[(row0 + qq) * N + col] = v;
      }
    }
  }
}

// ---------------- mean over 49 bins (bf16 input) ----------------
__global__ __launch_bounds__(256) void k_mean(const u16* __restrict__ H2,
                                              float* __restrict__ feat) {
  const int r = blockIdx.x;
  const int c = threadIdx.x * 2;
  float s0 = 0.f, s1 = 0.f;
#pragma unroll
  for (int qq = 0; qq < 49; ++qq) {
    unsigned v = *reinterpret_cast<const unsigned*>(&H2[((size_t)r * 49 + qq) * D2 + c]);
    s0 += bf2f((u16)(v & 0xffffu));
    s1 += bf2f((u16)(v >> 16));
  }
  feat[(size_t)r * D2 + c] = s0 * (1.0f / 49.0f);
  feat[(size_t)r * D2 + c + 1] = s1 * (1.0f / 49.0f);
}

// ---------------- pair gather ----------------
__global__ __launch_bounds__(256) void k_pairs(
    const float* __restrict__ feat, const int* __restrict__ num_obj,
    const int* __restrict__ pairs, float* __restrict__ out) {
  int r = blockIdx.x;
  int b = r >> 6;
  int off = 0;
  for (int i = 0; i < b; ++i) off += num_obj[i];
  int g0 = off + pairs[r * 2 + 0];
  int g1 = off + pairs[r * 2 + 1];
  for (int c = threadIdx.x; c < D2; c += 256) {
    out[(size_t)r * D2 + c] = 0.5f * (feat[(size_t)g0 * D2 + c] + feat[(size_t)g1 * D2 + c]);
  }
}

extern "C" void kernel_launch(void* const* d_in, const int* in_sizes, int n_in,
                              void* d_out, int out_size, void* d_ws, size_t ws_size,
                              hipStream_t stream) {
  const float* fmap = (const float*)d_in[0];
  const float* bboxes = (const float*)d_in[1];
  const int* num_obj = (const int*)d_in[2];
  const int* obj_pairs = (const int*)d_in[3];
  const int* pfw = (const int*)d_in[5];
  const int* pfh = (const int*)d_in[6];
  const float* W1 = (const float*)d_in[7];
  const float* b1 = (const float*)d_in[8];
  const float* W2 = (const float*)d_in[9];
  const float* b2 = (const float*)d_in[10];
  float* out = (float*)d_out;

  const size_t SZ_FMT = (size_t)BB * HW * CCH * 2;
  const size_t SZ_A   = (size_t)MROWS * D1 * 2;
  const size_t SZ_H1  = (size_t)MROWS * D1 * 2;
  const size_t SZ_W1B = (size_t)D1 * D1 * 2;
  const size_t SZ_W2B = (size_t)D1 * D2 * 2;

  char* ws = (char*)d_ws;
  u16* fmT = (u16*)ws;
  u16* A   = (u16*)(ws + SZ_FMT);
  u16* H1  = (u16*)(ws + SZ_FMT + SZ_A);
  u16* W1b = (u16*)(ws + SZ_FMT + SZ_A + SZ_H1);
  u16* W2b = (u16*)(ws + SZ_FMT + SZ_A + SZ_H1 + SZ_W1B);
  float* feat = (float*)(ws + SZ_FMT + SZ_A + SZ_H1 + SZ_W1B + SZ_W2B);
  u16* H2b = fmT;  // fmT dead after ROI align

  // all transposes in ONE launch: W1 (256 tiles) + W2 (128) + fmap (32*640)
  k_transpose_all<<<384 + BB * 640, 256, 0, stream>>>(W1, W1b, W2, W2b, fmap, fmT);

  k_roi_fast<<<dim3(NROI, 7), 128, 0, stream>>>(fmT, bboxes, pfw, pfh, A);

  k_gemm<D1, D1, 1><<<(MROWS / 128) * (D1 / 128), 256, 0, stream>>>(A, W1b, b1, (void*)H1);
  k_gemm<D1, D2, 1><<<(MROWS / 128) * (D2 / 128), 256, 0, stream>>>(H1, W2b, b2, (void*)H2b);
  k_mean<<<NROI, 256, 0, stream>>>(H2b, feat);
  k_pairs<<<BB * NREL, 256, 0, stream>>>(feat, num_obj, obj_pairs, out);
}

// Round 11
// 248.655 us; speedup vs baseline: 1.1301x; 1.0137x over previous
//
#include <hip/hip_runtime.h>

#define DEV __device__ __forceinline__

typedef unsigned short u16;
typedef short bf16x8 __attribute__((ext_vector_type(8)));
typedef float f32x4 __attribute__((ext_vector_type(4)));

// ---- problem constants (match reference) ----
#define BB    32
#define NOBJ  16
#define NREL  64
#define CCH   1024
#define FHW   50
#define HW    2500      // 50*50
#define NROI  512       // BB*NOBJ
#define MROWS 25088     // NROI*49  (= 196*128)
#define D1    1024
#define D2    512

DEV u16 f2bf(float f) {
  unsigned u = __float_as_uint(f);
  unsigned r = (u + 0x7FFFu + ((u >> 16) & 1u)) >> 16;
  return (u16)r;
}
DEV float bf2f(u16 h) { return __uint_as_float((unsigned)h << 16); }
DEV unsigned pk(float lo, float hi) { return (unsigned)f2bf(lo) | ((unsigned)f2bf(hi) << 16); }

using gvoid = __attribute__((address_space(1))) const void;
using svoid = __attribute__((address_space(3))) void;
DEV void gl_lds16(const void* g, void* s) {
  __builtin_amdgcn_global_load_lds((gvoid*)g, (svoid*)s, 16, 0, 0);
}

// ---------------- shared 64x64 transpose tile (f32 -> bf16) ----------------
DEV void transpose_tile(const float* __restrict__ in, u16* __restrict__ out,
                        int R, int C, int c0, int r0, int t) {
  __shared__ float tile[64][65];
  {
    const int rr = t >> 4;
    const int cq = (t & 15) * 4;
#pragma unroll
    for (int it = 0; it < 4; ++it) {
      int rl = rr + it * 16;
      int r = r0 + rl;
      int c = c0 + cq;
      if (c + 3 < C) {
        float4 v = *reinterpret_cast<const float4*>(&in[(size_t)r * C + c]);
        tile[rl][cq + 0] = v.x; tile[rl][cq + 1] = v.y;
        tile[rl][cq + 2] = v.z; tile[rl][cq + 3] = v.w;
      } else {
#pragma unroll
        for (int j = 0; j < 4; ++j)
          tile[rl][cq + j] = (c + j < C) ? in[(size_t)r * C + c + j] : 0.f;
      }
    }
  }
  __syncthreads();
  {
    const int c = t >> 2;
    const int rch = (t & 3) * 8;
    if (c0 + c < C) {
#pragma unroll
      for (int half = 0; half < 2; ++half) {
        int rb = rch + half * 32;
        uint4 o;
        o.x = pk(tile[rb + 0][c], tile[rb + 1][c]);
        o.y = pk(tile[rb + 2][c], tile[rb + 3][c]);
        o.z = pk(tile[rb + 4][c], tile[rb + 5][c]);
        o.w = pk(tile[rb + 6][c], tile[rb + 7][c]);
        *reinterpret_cast<uint4*>(&out[(size_t)(c0 + c) * R + r0 + rb]) = o;
      }
    }
  }
}

// ONE launch for all transposes: W1 (16x16 tiles), W2 (8x16 tiles),
// fmap (B * 40x16 tiles): (B, C=1024, HW=2500) f32 -> (B, HW, C) bf16
__global__ __launch_bounds__(256) void k_transpose_all(
    const float* __restrict__ W1, u16* __restrict__ W1b,
    const float* __restrict__ W2, u16* __restrict__ W2b,
    const float* __restrict__ fmap, u16* __restrict__ fmT) {
  const int bid = blockIdx.x;
  const int t = threadIdx.x;
  if (bid < 256) {          // W1: (D1 x D1)
    transpose_tile(W1, W1b, D1, D1, (bid & 15) * 64, (bid >> 4) * 64, t);
  } else if (bid < 384) {   // W2: (D1 x D2)
    const int b2 = bid - 256;
    transpose_tile(W2, W2b, D1, D2, (b2 & 7) * 64, (b2 >> 3) * 64, t);
  } else {                  // fmap: per batch 40 col-tiles x 16 row-tiles
    const int f = bid - 384;
    const int b = f / 640;
    const int rem = f - b * 640;
    const int cx = rem % 40, ry = rem / 40;
    transpose_tile(fmap + (size_t)b * CCH * HW, fmT + (size_t)b * CCH * HW,
                   CCH, HW, cx * 64, ry * 64, t);
  }
}

// ---------------- ROI align: dedup taps + static-variant dispatch ----------------
DEV void acc8v(uint4 v, float w, float* a) {
  a[0] = fmaf(w, bf2f((u16)(v.x & 0xffffu)), a[0]);
  a[1] = fmaf(w, bf2f((u16)(v.x >> 16)), a[1]);
  a[2] = fmaf(w, bf2f((u16)(v.y & 0xffffu)), a[2]);
  a[3] = fmaf(w, bf2f((u16)(v.y >> 16)), a[3]);
  a[4] = fmaf(w, bf2f((u16)(v.z & 0xffffu)), a[4]);
  a[5] = fmaf(w, bf2f((u16)(v.z >> 16)), a[5]);
  a[6] = fmaf(w, bf2f((u16)(v.w & 0xffffu)), a[6]);
  a[7] = fmaf(w, bf2f((u16)(v.w >> 16)), a[7]);
}

template <int YC, int XC>
DEV void bin_accum(const u16* bt, const int* yrow, const float* yw,
                   const int* xidx, const float* xw, float* a) {
  uint4 v[YC * XC];
#pragma unroll
  for (int jy = 0; jy < YC; ++jy)
#pragma unroll
    for (int jx = 0; jx < XC; ++jx)
      v[jy * XC + jx] =
          *reinterpret_cast<const uint4*>(bt + (size_t)(yrow[jy] + xidx[jx]) * CCH);
#pragma unroll
  for (int jy = 0; jy < YC; ++jy)
#pragma unroll
    for (int jx = 0; jx < XC; ++jx)
      acc8v(v[jy * XC + jx], yw[jy] * xw[jx], a);
}

// Flattened grid 3584 blocks with XCD-batch swizzle: XCD (bid&7) serves
// batches {xcd, xcd+8, xcd+16, xcd+24} -> per-XCD fmT working set ~1 batch
// (5.1 MB ~ L2) instead of all batches replicated into every XCD L2.
// Bijective: bid <-> (xcd, idx/112, roi_in_batch=wrem/7, py=wrem%7).
__global__ __launch_bounds__(128) void k_roi_fast(
    const u16* __restrict__ fmT, const float* __restrict__ bboxes,
    const int* __restrict__ pfw, const int* __restrict__ pfh,
    u16* __restrict__ Aout) {
  const int bid = blockIdx.x;
  const int xcd = bid & 7;
  const int idx = bid >> 3;           // 0..447
  const int b = xcd + 8 * (idx / 112);
  const int wrem = idx % 112;
  const int r = b * 16 + wrem / 7;    // roi
  const int py = wrem % 7;            // bin row
  const int t = threadIdx.x;
  const int c0 = t * 8;

  __shared__ int s_cnt[2][7];
  __shared__ int s_idx[2][7][4];
  __shared__ float s_wgt[2][7][4];

  int axis = -1, p = 0;
  if (t < 7) { axis = 0; p = t; }
  else if (t >= 64 && t < 71) { axis = 1; p = t - 64; }
  if (axis >= 0) {
    float fwf = (float)pfw[0], fhf = (float)pfh[0];
    // reference: im_height = frame_width, im_width = frame_height
    float hs = (float)FHW / fwf;
    float wsc = (float)FHW / fhf;
    float v1 = bboxes[r * 4 + (axis == 0 ? 1 : 0)] * (axis == 0 ? hs : wsc);
    float v2 = bboxes[r * 4 + (axis == 0 ? 3 : 2)] * (axis == 0 ? hs : wsc);
    float ext = fmaxf(v2 - v1, 1.0f);
    int idxq[4]; float wgt[4]; int cnt = 0;
#pragma unroll
    for (int j = 0; j < 2; ++j) {
      float g = (float)p + (j ? 0.75f : 0.25f);
      float coord = v1 + (ext / 7.0f) * g;
      float valid = (coord >= -1.0f && coord <= 50.0f) ? 1.0f : 0.0f;
      float cc = fmaxf(coord, 0.0f);
      int lo = (int)floorf(cc);
      bool edge = (lo >= FHW - 1);
      lo = min(lo, FHW - 1);
      int hi = min(lo + 1, FHW - 1);
      float l = edge ? 0.0f : (cc - (float)lo);
      float pr_i[2]; int pr_x[2];
      pr_x[0] = lo; pr_i[0] = valid * (1.0f - l);
      pr_x[1] = hi; pr_i[1] = valid * l;
#pragma unroll
      for (int e = 0; e < 2; ++e) {
        if (pr_i[e] != 0.0f) {
          bool found = false;
          for (int q = 0; q < cnt; ++q)
            if (idxq[q] == pr_x[e]) { wgt[q] += pr_i[e]; found = true; }
          if (!found) { idxq[cnt] = pr_x[e]; wgt[cnt] = pr_i[e]; ++cnt; }
        }
      }
    }
    s_cnt[axis][p] = cnt;
#pragma unroll
    for (int q = 0; q < 4; ++q) {
      s_idx[axis][p][q] = (q < cnt) ? idxq[q] : 0;
      s_wgt[axis][p][q] = (q < cnt) ? wgt[q] : 0.0f;
    }
  }
  __syncthreads();

  const u16* bt = fmT + (size_t)b * HW * CCH + c0;

  const int ycnt = s_cnt[0][py];
  int yrow[3]; float yw[3];
#pragma unroll
  for (int q = 0; q < 3; ++q) {
    yrow[q] = s_idx[0][py][q] * FHW;
    yw[q] = s_wgt[0][py][q];
  }

  for (int px = 0; px < 7; ++px) {
    const int xcnt = s_cnt[1][px];
    int xidx[3]; float xw[3];
#pragma unroll
    for (int q = 0; q < 3; ++q) {
      xidx[q] = s_idx[1][px][q];
      xw[q] = s_wgt[1][px][q];
    }
    float a[8] = {};
    switch (ycnt * 4 + xcnt) {
      case 1 * 4 + 1: bin_accum<1, 1>(bt, yrow, yw, xidx, xw, a); break;
      case 1 * 4 + 2: bin_accum<1, 2>(bt, yrow, yw, xidx, xw, a); break;
      case 1 * 4 + 3: bin_accum<1, 3>(bt, yrow, yw, xidx, xw, a); break;
      case 2 * 4 + 1: bin_accum<2, 1>(bt, yrow, yw, xidx, xw, a); break;
      case 2 * 4 + 2: bin_accum<2, 2>(bt, yrow, yw, xidx, xw, a); break;
      case 2 * 4 + 3: bin_accum<2, 3>(bt, yrow, yw, xidx, xw, a); break;
      case 3 * 4 + 1: bin_accum<3, 1>(bt, yrow, yw, xidx, xw, a); break;
      case 3 * 4 + 2: bin_accum<3, 2>(bt, yrow, yw, xidx, xw, a); break;
      case 3 * 4 + 3: bin_accum<3, 3>(bt, yrow, yw, xidx, xw, a); break;
      default: break;  // cnt==0 on an axis -> bin all zeros
    }
    u16* dst = Aout + (size_t)(r * 49 + py * 7 + px) * CCH + c0;
    uint4 o;
    o.x = pk(a[0] * 0.25f, a[1] * 0.25f);
    o.y = pk(a[2] * 0.25f, a[3] * 0.25f);
    o.z = pk(a[4] * 0.25f, a[5] * 0.25f);
    o.w = pk(a[6] * 0.25f, a[7] * 0.25f);
    *reinterpret_cast<uint4*>(dst) = o;
  }
}

// ---------------- GEMM: Out = relu(A @ Bt^T + bias), BK=64 + chunk swizzle ---
// PROVEN round-8 version (252.1 us, deterministic). Single LDS buffer,
// two barriers per K-tile (stage -> barrier -> read; barrier at loop top).
// 16B-chunk XOR swizzle phys_chunk = chunk ^ (row&7), applied both sides
// (rule #21). K-accumulation order = BK=32 order -> bit-identical output.
// NOTE round 9's 2-phase dbuf variant RACED (post-timing divergence) and was
// slower (64 KB LDS -> 2 blocks/CU); do not reintroduce without explicit
// vmcnt accounting + multi-run race screen.
template <int K, int N, int OBF>
__global__ __launch_bounds__(256) void k_gemm(
    const u16* __restrict__ A, const u16* __restrict__ Bt,
    const float* __restrict__ bias, void* __restrict__ Out) {
  __shared__ alignas(16) u16 As[128 * 64];
  __shared__ alignas(16) u16 Bs[128 * 64];
  const int t = threadIdx.x;
  const int lane = t & 63, w = t >> 6;
  const int wr = w >> 1, wc = w & 1;
  const int NT = N / 128;
  const int bid = blockIdx.x;
  const int chunk = (int)(gridDim.x >> 3);
  const int swz = (bid & 7) * chunk + (bid >> 3);
  const size_t m0 = (size_t)(swz / NT) * 128;
  const int n0 = (swz % NT) * 128;
  f32x4 acc[4][4] = {};

  // staging: thread t stages chunks i = t + 256*j (j=0..3) for A and B.
  // chunk i -> row = i>>3, logical col-chunk = i&7, source chunk = (i&7)^(row&7)
  int srow[4], scol[4];
#pragma unroll
  for (int j = 0; j < 4; ++j) {
    const int i = t + 256 * j;
    srow[j] = i >> 3;
    scol[j] = ((i & 7) ^ (srow[j] & 7)) * 8;  // element offset within row
  }

  for (int kt = 0; kt < K / 64; ++kt) {
    const int k0 = kt * 64;
    if (kt) __syncthreads();
#pragma unroll
    for (int j = 0; j < 4; ++j) {
      gl_lds16(A + (m0 + srow[j]) * K + k0 + scol[j], &As[(size_t)(t + 256 * j) * 8]);
      gl_lds16(Bt + (size_t)(n0 + srow[j]) * K + k0 + scol[j], &Bs[(size_t)(t + 256 * j) * 8]);
    }
    __syncthreads();

    bf16x8 av[2][4], bv[2][4];
#pragma unroll
    for (int ks = 0; ks < 2; ++ks) {
      const int lchunk = ks * 4 + (lane >> 4);  // logical 16B chunk in row
#pragma unroll
      for (int m = 0; m < 4; ++m) {
        const int row = wr * 64 + m * 16 + (lane & 15);
        av[ks][m] = *reinterpret_cast<const bf16x8*>(
            &As[row * 64 + (lchunk ^ (row & 7)) * 8]);
      }
#pragma unroll
      for (int n = 0; n < 4; ++n) {
        const int row = wc * 64 + n * 16 + (lane & 15);
        bv[ks][n] = *reinterpret_cast<const bf16x8*>(
            &Bs[row * 64 + (lchunk ^ (row & 7)) * 8]);
      }
    }
#pragma unroll
    for (int ks = 0; ks < 2; ++ks)
#pragma unroll
      for (int m = 0; m < 4; ++m)
#pragma unroll
        for (int n = 0; n < 4; ++n)
          asm("v_mfma_f32_16x16x32_bf16 %0, %1, %2, %0"
              : "+v"(acc[m][n]) : "v"(av[ks][m]), "v"(bv[ks][n]));
  }
  asm volatile("s_nop 7\n\ts_nop 7\n\ts_nop 7" ::);
#pragma unroll
  for (int n = 0; n < 4; ++n) {
    int col = n0 + wc * 64 + n * 16 + (lane & 15);
    float bb = bias[col];
#pragma unroll
    for (int m = 0; m < 4; ++m) {
      size_t row0 = m0 + wr * 64 + m * 16 + (lane >> 4) * 4;
#pragma unroll
      for (int qq = 0; qq < 4; ++qq) {
        float v = fmaxf(acc[m][n][qq] + bb, 0.0f);
        if (OBF) ((u16*)Out)[(row0 + qq) * N + col] = f2bf(v);
        else     ((float*)Out)[(row0 + qq) * N + col] = v;
      }
    }
  }
}

// ---------------- mean over 49 bins (bf16 input) ----------------
__global__ __launch_bounds__(256) void k_mean(const u16* __restrict__ H2,
                                              float* __restrict__ feat) {
  const int r = blockIdx.x;
  const int c = threadIdx.x * 2;
  float s0 = 0.f, s1 = 0.f;
#pragma unroll
  for (int qq = 0; qq < 49; ++qq) {
    unsigned v = *reinterpret_cast<const unsigned*>(&H2[((size_t)r * 49 + qq) * D2 + c]);
    s0 += bf2f((u16)(v & 0xffffu));
    s1 += bf2f((u16)(v >> 16));
  }
  feat[(size_t)r * D2 + c] = s0 * (1.0f / 49.0f);
  feat[(size_t)r * D2 + c + 1] = s1 * (1.0f / 49.0f);
}

// ---------------- pair gather ----------------
__global__ __launch_bounds__(256) void k_pairs(
    const float* __restrict__ feat, const int* __restrict__ num_obj,
    const int* __restrict__ pairs, float* __restrict__ out) {
  int r = blockIdx.x;
  int b = r >> 6;
  int off = 0;
  for (int i = 0; i < b; ++i) off += num_obj[i];
  int g0 = off + pairs[r * 2 + 0];
  int g1 = off + pairs[r * 2 + 1];
  for (int c = threadIdx.x; c < D2; c += 256) {
    out[(size_t)r * D2 + c] = 0.5f * (feat[(size_t)g0 * D2 + c] + feat[(size_t)g1 * D2 + c]);
  }
}

extern "C" void kernel_launch(void* const* d_in, const int* in_sizes, int n_in,
                              void* d_out, int out_size, void* d_ws, size_t ws_size,
                              hipStream_t stream) {
  const float* fmap = (const float*)d_in[0];
  const float* bboxes = (const float*)d_in[1];
  const int* num_obj = (const int*)d_in[2];
  const int* obj_pairs = (const int*)d_in[3];
  const int* pfw = (const int*)d_in[5];
  const int* pfh = (const int*)d_in[6];
  const float* W1 = (const float*)d_in[7];
  const float* b1 = (const float*)d_in[8];
  const float* W2 = (const float*)d_in[9];
  const float* b2 = (const float*)d_in[10];
  float* out = (float*)d_out;

  const size_t SZ_FMT = (size_t)BB * HW * CCH * 2;
  const size_t SZ_A   = (size_t)MROWS * D1 * 2;
  const size_t SZ_H1  = (size_t)MROWS * D1 * 2;
  const size_t SZ_W1B = (size_t)D1 * D1 * 2;
  const size_t SZ_W2B = (size_t)D1 * D2 * 2;

  char* ws = (char*)d_ws;
  u16* fmT = (u16*)ws;
  u16* A   = (u16*)(ws + SZ_FMT);
  u16* H1  = (u16*)(ws + SZ_FMT + SZ_A);
  u16* W1b = (u16*)(ws + SZ_FMT + SZ_A + SZ_H1);
  u16* W2b = (u16*)(ws + SZ_FMT + SZ_A + SZ_H1 + SZ_W1B);
  float* feat = (float*)(ws + SZ_FMT + SZ_A + SZ_H1 + SZ_W1B + SZ_W2B);
  u16* H2b = fmT;  // fmT dead after ROI align

  // all transposes in ONE launch: W1 (256 tiles) + W2 (128) + fmap (32*640)
  k_transpose_all<<<384 + BB * 640, 256, 0, stream>>>(W1, W1b, W2, W2b, fmap, fmT);

  k_roi_fast<<<NROI * 7, 128, 0, stream>>>(fmT, bboxes, pfw, pfh, A);

  k_gemm<D1, D1, 1><<<(MROWS / 128) * (D1 / 128), 256, 0, stream>>>(A, W1b, b1, (void*)H1);
  k_gemm<D1, D2, 1><<<(MROWS / 128) * (D2 / 128), 256, 0, stream>>>(H1, W2b, b2, (void*)H2b);
  k_mean<<<NROI, 256, 0, stream>>>(H2b, feat);
  k_pairs<<<BB * NREL, 256, 0, stream>>>(feat, num_obj, obj_pairs, out);
}